// Round 5
// baseline (668.246 us; speedup 1.0000x reference)
//
#include <hip/hip_runtime.h>

// DeltaNet chunkwise delta rule. b=2,h=8,L=4096,d=128,chunk=32.
// R5: scan prefetch moved from registers (R4 — defeated by regalloc, VGPR=224
// vs ~350 needed) to LDS via global_load_lds DMA (zero VGPR, can't be sunk):
//   - prep packs per-(head,chunk) operands into a lane-order blob:
//     34 slots x 1KB; slot = one wave-wide frag (16B/lane) in exact read order.
//   - scan: 4-deep LDS ring (4x28KB), DMA chunk ch+2 during chunk ch,
//     hand-placed s_waitcnt vmcnt(28) (imm 0x4F7C) + sched_barrier(0).
//   - u stored bf16 (only ever consumed as bf16 uB) -> ws 71.3MB (<76MB, R2-proven).
// Compute per chunk (unchanged from R4, verified): 26 v_mfma_f32_32x32x16_bf16.

#define Bb 2
#define Hh 8
#define Ll 4096
#define Dd 128
#define DP (Dd + 4)
#define Cc 32
#define CP (Cc + 4)
#define NC (Ll / Cc)       // 128 chunks
#define BHn (Bb * Hh)      // 16 heads
#define SLOTS 34           // blob slots per chunk: 8 wA, 8 qa, 8 kA, 2 attn, 8 u
#define WSLOTS 28          // slots one wave DMAs: 26 shared + its 2 u slots

typedef float  f32x16 __attribute__((ext_vector_type(16)));
typedef short  bf16x8 __attribute__((ext_vector_type(8)));

__device__ __forceinline__ short f2bf(float x) {
    union { float f; unsigned u; } a; a.f = x;
    const unsigned r = a.u + 0x7FFFu + ((a.u >> 16) & 1u);  // RNE
    return (short)(r >> 16);
}
__device__ __forceinline__ float bf2f(short x) {
    union { unsigned u; float f; } t;
    t.u = ((unsigned)(unsigned short)x) << 16;
    return t.f;
}
__device__ __forceinline__ void async16(const short* g, short* l) {
    __builtin_amdgcn_global_load_lds(
        (const __attribute__((address_space(1))) unsigned int*)g,
        (__attribute__((address_space(3))) unsigned int*)l, 16, 0, 0);
}

// ---------------------------------------------------------------------------
// Kernel 1: per-(head,chunk) precompute -> packed blob. 2048 blocks x 256.
// Blob slot map (lane l = 32h + c; 8 bf16 per lane per slot):
//  i in [0,8)  : wA  : -w[c][16i+8h+j]
//  i in [8,16) : qa  : qn[c][16(i-8)+8h+j]
//  i in [16,24): kA  : t=(i-16)>>1, m=(i-16)&1 : kn[16m+8h+j][32t+c]
//  i in [24,26): atA : attn[c][16(i-24)+8h+j]
//  i in [26,34): u   : g=(i-26)>>1, jj=(i-26)&1 :
//                      u[(e&3)+16jj+8(e>>2)+4h][32g+c]  (e = elem idx)
// ---------------------------------------------------------------------------
__global__ __launch_bounds__(256) void prep_kernel(
    const float* __restrict__ q, const float* __restrict__ k,
    const float* __restrict__ v, const float* __restrict__ beta,
    short* __restrict__ blob)
{
    __shared__ float sK[Cc][DP];
    __shared__ float sQ[Cc][DP];
    __shared__ float sV[Cc][DP];   // v*beta, later overwritten with u
    __shared__ float sW[Cc][DP];   // -w
    __shared__ float sA[Cc][CP];   // A, later overwritten with attn
    __shared__ float sInv[Cc][CP];
    __shared__ float sBeta[Cc], sNk[Cc], sNq[Cc];

    const int tid = threadIdx.x;
    const int blk = blockIdx.x;          // bh*NC + ch
    const int bh = blk / NC;
    const int ch = blk % NC;
    const size_t base = (size_t)(bh * Ll + ch * Cc) * Dd;

    for (int e = tid; e < Cc * Dd / 4; e += 256) {
        const int r = e >> 5, c4 = e & 31;
        ((float4*)&sQ[r][0])[c4] = ((const float4*)(q + base))[e];
        ((float4*)&sK[r][0])[c4] = ((const float4*)(k + base))[e];
        ((float4*)&sV[r][0])[c4] = ((const float4*)(v + base))[e];
    }
    if (tid < Cc) sBeta[tid] = beta[bh * Ll + ch * Cc + tid];
    __syncthreads();

    // row norms: 4 lanes per row, rows 0..31 = k, 32..63 = q
    {
        const int row = tid >> 2, part = tid & 3;
        const float* src = (row < Cc) ? &sK[row][0] : &sQ[row - Cc][0];
        float s = 0.f;
        #pragma unroll
        for (int j = 0; j < 8; ++j) {
            const float4 t = ((const float4*)src)[part + j * 4];
            s += t.x * t.x + t.y * t.y + t.z * t.z + t.w * t.w;
        }
        s += __shfl_xor(s, 1);
        s += __shfl_xor(s, 2);
        if (part == 0) {
            const float r = 1.0f / sqrtf(s);
            if (row < Cc) sNk[row] = r; else sNq[row - Cc] = r;
        }
    }
    __syncthreads();

    for (int e = tid; e < Cc * Dd / 4; e += 256) {
        const int r = e >> 5, c4 = e & 31;
        float4 kk = ((float4*)&sK[r][0])[c4];
        float4 qq = ((float4*)&sQ[r][0])[c4];
        float4 vv = ((float4*)&sV[r][0])[c4];
        const float nk = sNk[r], nq = sNq[r], bb = sBeta[r];
        kk.x *= nk; kk.y *= nk; kk.z *= nk; kk.w *= nk;
        qq.x *= nq; qq.y *= nq; qq.z *= nq; qq.w *= nq;
        vv.x *= bb; vv.y *= bb; vv.z *= bb; vv.w *= bb;
        ((float4*)&sK[r][0])[c4] = kk;
        ((float4*)&sQ[r][0])[c4] = qq;
        ((float4*)&sV[r][0])[c4] = vv;
    }
    __syncthreads();

    // A[i][j] = beta_i * dot(kn_i, kn_j); sInv = I
    for (int e = tid; e < Cc * Cc; e += 256) {
        const int i = e >> 5, j = e & 31;
        const float4* ri = (const float4*)&sK[i][0];
        const float4* rj = (const float4*)&sK[j][0];
        float s = 0.f;
        for (int x = 0; x < Dd / 4; ++x) {
            const float4 a = ri[x], b = rj[x];
            s += a.x * b.x + a.y * b.y + a.z * b.z + a.w * b.w;
        }
        sA[i][j] = s * sBeta[i];
        sInv[i][j] = (i == j) ? 1.0f : 0.0f;
    }
    __syncthreads();

    // forward substitution (unit lower triangular inverse)
    for (int i = 1; i < Cc; ++i) {
        if (tid < i) {
            const int j = tid;
            float s = 0.f;
            for (int m = j; m < i; ++m) s += sA[i][m] * sInv[m][j];
            sInv[i][j] = -s;
        }
        __syncthreads();
    }

    // u = inv @ (v*beta), w = -(inv @ (kn*beta))  -> registers first
    float uu[16], ww[16];
    #pragma unroll
    for (int t = 0; t < 16; ++t) {
        const int e = tid + t * 256;
        const int c = e >> 7, dd = e & 127;
        float su = 0.f, sw = 0.f;
        for (int f = 0; f <= c; ++f) {
            const float iv = sInv[c][f];
            su += iv * sV[f][dd];
            sw += iv * sBeta[f] * sK[f][dd];
        }
        uu[t] = su;
        ww[t] = -sw;
    }
    // attn = tril(qn @ kn^T) -> registers
    float at[4];
    #pragma unroll
    for (int t = 0; t < 4; ++t) {
        const int e = tid + t * 256;
        const int i = e >> 5, j = e & 31;
        float s = 0.f;
        if (j <= i) {
            const float4* ri = (const float4*)&sQ[i][0];
            const float4* rj = (const float4*)&sK[j][0];
            for (int x = 0; x < Dd / 4; ++x) {
                const float4 a = ri[x], b = rj[x];
                s += a.x * b.x + a.y * b.y + a.z * b.z + a.w * b.w;
            }
        }
        at[t] = s;
    }
    __syncthreads();   // all reads of sV/sA complete before overwrite

    #pragma unroll
    for (int t = 0; t < 16; ++t) {
        const int e = tid + t * 256;
        const int c = e >> 7, dd = e & 127;
        sV[c][dd] = uu[t];       // u
        sW[c][dd] = ww[t];       // -w
    }
    #pragma unroll
    for (int t = 0; t < 4; ++t) {
        const int e = tid + t * 256;
        sA[e >> 5][e & 31] = at[t];   // attn
    }
    __syncthreads();

    // emit blob: 34 slots x 64 lanes x 16B, lane-interleaved (coalesced)
    const size_t cOff = (size_t)blk * (SLOTS * 512);   // in shorts
    for (int s = tid; s < SLOTS * 64; s += 256) {
        const int i = s >> 6, l = s & 63;
        const int hh = l >> 5, cc = l & 31;
        bf16x8 r;
        if (i < 16) {                         // wA (-w) or qa (qn)
            const float* src = (i < 8) ? &sW[cc][0] : &sQ[cc][0];
            const int k0 = 16 * (i & 7) + 8 * hh;
            #pragma unroll
            for (int j = 0; j < 8; ++j) r[j] = f2bf(src[k0 + j]);
        } else if (i < 24) {                  // kA: kn^T frags
            const int t2 = (i - 16) >> 1, m = (i - 16) & 1;
            const int k0 = 16 * m + 8 * hh;
            #pragma unroll
            for (int j = 0; j < 8; ++j) r[j] = f2bf(sK[k0 + j][32 * t2 + cc]);
        } else if (i < 26) {                  // attn frags
            const int k0 = 16 * (i - 24) + 8 * hh;
            #pragma unroll
            for (int j = 0; j < 8; ++j) r[j] = f2bf(sA[cc][k0 + j]);
        } else {                              // u frags (C-layout rows)
            const int gg = (i - 26) >> 1, jj = (i - 26) & 1;
            #pragma unroll
            for (int e2 = 0; e2 < 8; ++e2)
                r[e2] = f2bf(
                    sV[(e2 & 3) + 16 * jj + 8 * (e2 >> 2) + 4 * hh][32 * gg + cc]);
        }
        ((bf16x8*)(blob + cOff))[s] = r;
    }
}

// ---------------------------------------------------------------------------
// Kernel 2: MFMA scan with LDS-ring DMA prefetch.
// Grid (16 heads, 4 col-groups) x 64 threads (1 wave).
// ---------------------------------------------------------------------------
__global__ __launch_bounds__(64, 1) void scan_kernel(
    const short* __restrict__ blob, float* __restrict__ out)
{
    __shared__ short lds[4][WSLOTS * 512];   // 4 x 28KB ring

    const int lane = threadIdx.x;
    const int h = lane >> 5;
    const int c = lane & 31;
    const int bh = blockIdx.x;
    const int g = blockIdx.y;
    const int colBase = g * 32;

    f32x16 S0, S1, S2, S3;
    #pragma unroll
    for (int r = 0; r < 16; ++r) { S0[r]=0.f; S1[r]=0.f; S2[r]=0.f; S3[r]=0.f; }

    auto issue = [&](int ch, int buf) {
        const short* gB = blob + (size_t)(bh * NC + ch) * (SLOTS * 512) + lane * 8;
        short* lB = &lds[buf][0];
        #pragma unroll
        for (int i = 0; i < 26; ++i)
            async16(gB + i * 512, lB + i * 512);
        #pragma unroll
        for (int j = 0; j < 2; ++j)
            async16(gB + (26 + 2 * g + j) * 512, lB + (26 + j) * 512);
    };

    issue(0, 0);
    issue(1, 1);

    for (int ch = 0; ch < NC; ++ch) {
        // wait for chunk ch's 28 DMAs (28 newer ops = next chunk's may remain)
        __builtin_amdgcn_s_waitcnt(0x4F7C);      // vmcnt(28)
        __builtin_amdgcn_sched_barrier(0);

        const short* lb = &lds[ch & 3][0];
        bf16x8 wA[8], qa[8], kA[8], atA[2], ub[2];
        #pragma unroll
        for (int i = 0; i < 8; ++i)
            wA[i] = *(const bf16x8*)(lb + i * 512 + lane * 8);
        #pragma unroll
        for (int i = 0; i < 8; ++i)
            qa[i] = *(const bf16x8*)(lb + (8 + i) * 512 + lane * 8);
        #pragma unroll
        for (int i = 0; i < 8; ++i)
            kA[i] = *(const bf16x8*)(lb + (16 + i) * 512 + lane * 8);
        atA[0] = *(const bf16x8*)(lb + 24 * 512 + lane * 8);
        atA[1] = *(const bf16x8*)(lb + 25 * 512 + lane * 8);
        ub[0]  = *(const bf16x8*)(lb + 26 * 512 + lane * 8);
        ub[1]  = *(const bf16x8*)(lb + 27 * 512 + lane * 8);

        // prefetch chunk ch+2 into ring slot (ch+2)&3 (last read at ch-2)
        const int nx = (ch + 2 < NC) ? ch + 2 : NC - 1;
        issue(nx, (ch + 2) & 3);

        // ---- compute (R4-verified): U = u - w@S ; O = qn@S + attn@u_adj ----
        f32x16 U1, U2, O;
        #pragma unroll
        for (int j = 0; j < 2; ++j)
            #pragma unroll
            for (int e = 0; e < 8; ++e)
                U1[8 * j + e] = bf2f(ub[j][e]);
        #pragma unroll
        for (int r = 0; r < 16; ++r) { U2[r] = 0.f; O[r] = 0.f; }

        #pragma unroll
        for (int ks = 0; ks < 8; ++ks) {
            const f32x16& T = (ks < 2) ? S0 : (ks < 4) ? S1 : (ks < 6) ? S2 : S3;
            const int m = ks & 1;
            bf16x8 sB;   // S C-layout -> B-operand via shfl_xor(.,32)
            #pragma unroll
            for (int i = 0; i < 4; ++i) {
                const float A = T[8 * m + i];
                const float Bv = T[8 * m + 4 + i];
                const float z = h ? A : Bv;
                const float rr = __shfl_xor(z, 32);
                sB[i]     = f2bf(h ? rr : A);
                sB[4 + i] = f2bf(h ? Bv : rr);
            }
            if (ks < 4)
                U1 = __builtin_amdgcn_mfma_f32_32x32x16_bf16(wA[ks], sB, U1, 0, 0, 0);
            else
                U2 = __builtin_amdgcn_mfma_f32_32x32x16_bf16(wA[ks], sB, U2, 0, 0, 0);
            O = __builtin_amdgcn_mfma_f32_32x32x16_bf16(qa[ks], sB, O, 0, 0, 0);
        }

        f32x16 U;
        #pragma unroll
        for (int r = 0; r < 16; ++r) U[r] = U1[r] + U2[r];

        bf16x8 uB[2];
        #pragma unroll
        for (int m = 0; m < 2; ++m) {
            #pragma unroll
            for (int i = 0; i < 4; ++i) {
                const float A = U[8 * m + i];
                const float Bv = U[8 * m + 4 + i];
                const float z = h ? A : Bv;
                const float rr = __shfl_xor(z, 32);
                uB[m][i]     = f2bf(h ? rr : A);
                uB[m][4 + i] = f2bf(h ? Bv : rr);
            }
        }
        O = __builtin_amdgcn_mfma_f32_32x32x16_bf16(atA[0], uB[0], O, 0, 0, 0);
        O = __builtin_amdgcn_mfma_f32_32x32x16_bf16(atA[1], uB[1], O, 0, 0, 0);

        const size_t qb = (size_t)(bh * Ll + ch * Cc) * Dd;
        #pragma unroll
        for (int r = 0; r < 16; ++r) {
            const int row = (r & 3) + 8 * (r >> 2) + 4 * h;
            out[qb + (size_t)row * Dd + colBase + c] = O[r];
        }

        S0 = __builtin_amdgcn_mfma_f32_32x32x16_bf16(kA[0], uB[0], S0, 0, 0, 0);
        S0 = __builtin_amdgcn_mfma_f32_32x32x16_bf16(kA[1], uB[1], S0, 0, 0, 0);
        S1 = __builtin_amdgcn_mfma_f32_32x32x16_bf16(kA[2], uB[0], S1, 0, 0, 0);
        S1 = __builtin_amdgcn_mfma_f32_32x32x16_bf16(kA[3], uB[1], S1, 0, 0, 0);
        S2 = __builtin_amdgcn_mfma_f32_32x32x16_bf16(kA[4], uB[0], S2, 0, 0, 0);
        S2 = __builtin_amdgcn_mfma_f32_32x32x16_bf16(kA[5], uB[1], S2, 0, 0, 0);
        S3 = __builtin_amdgcn_mfma_f32_32x32x16_bf16(kA[6], uB[0], S3, 0, 0, 0);
        S3 = __builtin_amdgcn_mfma_f32_32x32x16_bf16(kA[7], uB[1], S3, 0, 0, 0);
    }

    // S_final -> d_out tail
    const size_t soff = (size_t)Bb * Hh * Ll * Dd;
    #pragma unroll
    for (int t = 0; t < 4; ++t) {
        const f32x16& T = (t == 0) ? S0 : (t == 1) ? S1 : (t == 2) ? S2 : S3;
        #pragma unroll
        for (int r = 0; r < 16; ++r) {
            const int row = 32 * t + (r & 3) + 8 * (r >> 2) + 4 * h;
            out[soff + (size_t)bh * Dd * Dd + (size_t)row * Dd + colBase + c] =
                T[r];
        }
    }
}

extern "C" void kernel_launch(void* const* d_in, const int* in_sizes, int n_in,
                              void* d_out, int out_size, void* d_ws,
                              size_t ws_size, hipStream_t stream) {
    const float* q    = (const float*)d_in[0];
    const float* k    = (const float*)d_in[1];
    const float* v    = (const float*)d_in[2];
    const float* beta = (const float*)d_in[3];
    float* out = (float*)d_out;
    short* blob = (short*)d_ws;   // 2048 chunks x 34KB = 71.3MB (<76MB proven)

    prep_kernel<<<dim3(BHn * NC), 256, 0, stream>>>(q, k, v, beta, blob);
    scan_kernel<<<dim3(BHn, 4), 64, 0, stream>>>(blob, out);
}